// Round 13
// baseline (185.018 us; speedup 1.0000x reference)
//
#include <hip/hip_runtime.h>
#include <hip/hip_bf16.h>
#include <stdint.h>

#define NB 32
#define NS 2048
#define NH 1024

typedef __attribute__((ext_vector_type(8))) unsigned short ushort8v;
typedef __attribute__((ext_vector_type(4))) unsigned short ushort4v;
typedef __attribute__((ext_vector_type(8))) __bf16 bf16x8;
typedef __attribute__((ext_vector_type(4))) float floatx4;

__device__ __forceinline__ unsigned short f2bf(float f) {
    union { float f; unsigned int u; } x; x.f = f;
    unsigned int r = x.u + 0x7fffu + ((x.u >> 16) & 1u);
    return (unsigned short)(r >> 16);
}
__device__ __forceinline__ float bf2f(unsigned short u) {
    union { unsigned int u; float f; } x; x.u = ((unsigned int)u) << 16;
    return x.f;
}
__device__ __forceinline__ float tanh_fast(float x) {
    float e2 = __expf(2.0f * x);
    return 1.0f - 2.0f * __builtin_amdgcn_rcpf(e2 + 1.0f);
}
__device__ __forceinline__ void gload_lds16(const void* g, void* l) {
    __builtin_amdgcn_global_load_lds(
        (const __attribute__((address_space(1))) unsigned int*)g,
        (__attribute__((address_space(3))) unsigned int*)l, 16, 0, 0);
}

// ---------- Kernel E: E f32 -> Ebf bf16 (valid rows; ALL rows if len==0) ----
__global__ void conve_kernel(const float* __restrict__ E,
                             const int* __restrict__ lens,
                             unsigned short* __restrict__ Ebf)
{
    int r = blockIdx.x;                   // 65536 rows
    int len = lens[r >> 11];
    if (len != 0 && (r & (NS - 1)) >= len) return;
    int t = threadIdx.x;                  // 256
    float4 f = *(const float4*)(E + (size_t)r * NH + t * 4);
    ushort4v u;
    u[0] = f2bf(f.x); u[1] = f2bf(f.y); u[2] = f2bf(f.z); u[3] = f2bf(f.w);
    *(ushort4v*)(Ebf + (size_t)r * NH + t * 4) = u;
}

// ---------- Kernel WP: fused convw (blocks 0..127) + projs (blocks 128..255) -
__global__ void convw_projs_kernel(const float* __restrict__ Wh,
                                   unsigned short* __restrict__ WhP,
                                   const float* __restrict__ q,
                                   const float* __restrict__ Ws,
                                   float* __restrict__ projs)
{
    int t = threadIdx.x;                  // 256
    if (blockIdx.x < 128) {
        int kb = blockIdx.x;
        int n  = t * 4;
        int ni = n & 15, nh = n >> 4;
        for (int i = 0; i < 8; ++i) {
            int k = kb * 8 + i;
            float4 w = *(const float4*)(Wh + (size_t)k * NH + n);
            size_t base = (size_t)nh * 16384 + (size_t)(k >> 5) * 512 + (k & 31);
            WhP[base + (size_t)(ni + 0) * 32] = f2bf(w.x);
            WhP[base + (size_t)(ni + 1) * 32] = f2bf(w.y);
            WhP[base + (size_t)(ni + 2) * 32] = f2bf(w.z);
            WhP[base + (size_t)(ni + 3) * 32] = f2bf(w.w);
        }
        return;
    }
    int lb = blockIdx.x - 128;            // 32 b x 4 d-chunks
    int b  = lb >> 2;
    int d0 = (lb & 3) * 256;
    int kg = t >> 6;
    int dc = t & 63;
    const float* qb = q + (size_t)b * NH;
    float4 acc = {0.f, 0.f, 0.f, 0.f};
    for (int k = kg * 256; k < kg * 256 + 256; ++k) {
        float qv = qb[k];
        float4 wv = *(const float4*)(Ws + (size_t)k * NH + d0 + dc * 4);
        acc.x += qv * wv.x; acc.y += qv * wv.y;
        acc.z += qv * wv.z; acc.w += qv * wv.w;
    }
    __shared__ float4 red[4][64];
    red[kg][dc] = acc;
    __syncthreads();
    if (t < 64) {
        float4 s = red[0][t];
        float4 s1 = red[1][t], s2 = red[2][t], s3 = red[3][t];
        s.x += s1.x + s2.x + s3.x; s.y += s1.y + s2.y + s3.y;
        s.z += s1.z + s2.z + s3.z; s.w += s1.w + s2.w + s3.w;
        *(float4*)(projs + (size_t)b * NH + d0 + t * 4) = s;
    }
}

// ---------- Kernel B: 128x256 GEMM, 4 waves (2x2), wave tile 64x128 ---------
// acc 4x8 frags = 128 f32/lane. LDS bytes per K-step: 48 KB read (A dup2 +
// B dup2) + 24 KB write = 72 KB (was 88 with 8x(64x64) waves). 3-buffer ring,
// single barrier per K-step, counted vmcnt(6). XCD-chunked grid swizzle.
__global__ __launch_bounds__(256) void scores_kernel(
    const unsigned short* __restrict__ Ebf, const unsigned short* __restrict__ WhP,
    const float* __restrict__ projs, const float* __restrict__ v,
    const int* __restrict__ lens, float* __restrict__ spart)
{
    __shared__ __align__(16) unsigned short Al[3][4096];  // [128 rows][32 sh] x3
    __shared__ __align__(16) unsigned short Bl[3][8192];  // 16 x 1KB units  x3
    __shared__ float sc[2][128];

    const int tid  = threadIdx.x;
    const int wgid = blockIdx.x;
    const int vid  = (wgid & 7) * 256 + (wgid >> 3);   // XCD-chunked swizzle
    const int brow = (vid >> 2) * 128;
    const int cb   = vid & 3;             // 0..3: cols [cb*256, +256)
    const int b    = brow >> 11;
    const int sloc = brow & (NS - 1);
    if (sloc >= lens[b]) return;

    const int wave = tid >> 6;            // 0..3
    const int lane = tid & 63;
    const int l15 = lane & 15;
    const int l16 = lane >> 4;
    const int wr = wave >> 1;             // 0..1 row grp (64 rows)
    const int wc = wave & 1;              // 0..1 col grp (128 cols)

    floatx4 acc[4][8];
    #pragma unroll
    for (int m = 0; m < 4; ++m)
        #pragma unroll
        for (int c = 0; c < 8; ++c) acc[m][c] = (floatx4){0.f, 0.f, 0.f, 0.f};

    // source-side swizzle (involution, same for A and B)
    const int ssw = ((lane & 3) ^ ((lane >> 3) & 3)) * 8;

    // A staging: wave stages units {wave, wave+4} (rows 16u..16u+16)
    const unsigned short* Asrc0 = Ebf
        + (size_t)(brow + wave * 16 + (lane >> 2)) * NH + ssw;
    const unsigned short* Asrc1 = Asrc0 + (size_t)64 * NH;
    // B staging: wave stages units wave*4 .. wave*4+3 (1KB each in WhP)
    const unsigned short* Bsrc = WhP
        + (size_t)(cb * 16 + wave * 4) * 16384 + (lane >> 2) * 32 + ssw;

    #define STAGE(buf, kc)                                                     \
    {                                                                          \
        gload_lds16(Asrc0 + (size_t)(kc) * 32, (void*)&Al[buf][wave * 512]);   \
        gload_lds16(Asrc1 + (size_t)(kc) * 32, (void*)&Al[buf][(wave + 4) * 512]); \
        _Pragma("unroll")                                                      \
        for (int u = 0; u < 4; ++u)                                            \
            gload_lds16(Bsrc + (size_t)u * 16384 + (size_t)(kc) * 512,         \
                        (void*)&Bl[buf][(wave * 4 + u) * 512]);                \
    }

    const int aslot = (l16 ^ ((l15 >> 1) & 3)) * 8;
    const int bslot = aslot;

    #define COMPUTE(buf)                                                       \
    {                                                                          \
        bf16x8 a[4], bfr[8];                                                   \
        _Pragma("unroll")                                                      \
        for (int m = 0; m < 4; ++m)                                            \
            a[m] = __builtin_bit_cast(bf16x8, *(const ushort8v*)               \
                &Al[buf][(wr * 64 + m * 16 + l15) * 32 + aslot]);              \
        _Pragma("unroll")                                                      \
        for (int c = 0; c < 8; ++c)                                            \
            bfr[c] = __builtin_bit_cast(bf16x8, *(const ushort8v*)             \
                &Bl[buf][(wc * 8 + c) * 512 + l15 * 32 + bslot]);              \
        __builtin_amdgcn_s_setprio(1);                                         \
        _Pragma("unroll")                                                      \
        for (int m = 0; m < 4; ++m)                                            \
            _Pragma("unroll")                                                  \
            for (int c = 0; c < 8; ++c)                                        \
                acc[m][c] = __builtin_amdgcn_mfma_f32_16x16x32_bf16(           \
                    a[m], bfr[c], acc[m][c], 0, 0, 0);                         \
        __builtin_amdgcn_s_setprio(0);                                         \
    }

    STAGE(0, 0);

    for (int kc = 0; kc < 31; ++kc) {
        const int rbuf = kc % 3;
        const int sbuf = (kc + 1) % 3;
        STAGE(sbuf, kc + 1);
        // outstanding: tile kc (6, oldest) + tile kc+1 (6); wait tile kc only
        asm volatile("s_waitcnt vmcnt(6)" ::: "memory");
        __builtin_amdgcn_sched_barrier(0);
        __builtin_amdgcn_s_barrier();
        COMPUTE(rbuf);
    }
    // tail: kc = 31 (staged in iter 30)
    asm volatile("s_waitcnt vmcnt(0)" ::: "memory");
    __builtin_amdgcn_sched_barrier(0);
    __builtin_amdgcn_s_barrier();
    COMPUTE(31 % 3);
    #undef STAGE
    #undef COMPUTE

    // epilogue: partial score over this cb's 256 cols (wave owns 128 of them)
    float psv[8], vv[8];
    #pragma unroll
    for (int c = 0; c < 8; ++c) {
        int col = cb * 256 + wc * 128 + c * 16 + l15;
        psv[c] = projs[(size_t)b * NH + col];
        vv[c]  = v[col];
    }
    #pragma unroll
    for (int m = 0; m < 4; ++m) {
        float sp[4] = {0.f, 0.f, 0.f, 0.f};
        #pragma unroll
        for (int c = 0; c < 8; ++c)
            #pragma unroll
            for (int i = 0; i < 4; ++i)
                sp[i] += tanh_fast(acc[m][c][i] + psv[c]) * vv[c];
        #pragma unroll
        for (int i = 0; i < 4; ++i) {
            float s = sp[i];
            s += __shfl_xor(s, 1);
            s += __shfl_xor(s, 2);
            s += __shfl_xor(s, 4);
            s += __shfl_xor(s, 8);
            if (l15 == 0) sc[wc][wr * 64 + m * 16 + l16 * 4 + i] = s;
        }
    }
    __syncthreads();
    if (tid < 128) {
        float s = sc[0][tid] + sc[1][tid];
        spart[(size_t)cb * (NB * NS) + brow + tid] = s;
    }
}

// ---------- Kernel C1: masked softmax (sums 4 column partials) --------------
__global__ void softmax_kernel(const float* __restrict__ spart,
                               const int* __restrict__ lens,
                               float* __restrict__ wts)
{
    int b = blockIdx.x, tid = threadIdx.x;      // 32 x 256
    int len = lens[b];
    float loc[8];
    float mx = -3e38f;
    #pragma unroll
    for (int i = 0; i < 8; ++i) {
        int s = tid + i * 256;
        float val = -1e9f;
        if (s < len) {
            val = 0.f;
            #pragma unroll
            for (int c = 0; c < 4; ++c)
                val += spart[(size_t)c * (NB * NS) + (size_t)b * NS + s];
        }
        loc[i] = val;
        mx = fmaxf(mx, val);
    }
    #pragma unroll
    for (int m = 32; m >= 1; m >>= 1) mx = fmaxf(mx, __shfl_xor(mx, m));
    __shared__ float red[4], red2[4];
    int w = tid >> 6;
    if ((tid & 63) == 0) red[w] = mx;
    __syncthreads();
    mx = fmaxf(fmaxf(red[0], red[1]), fmaxf(red[2], red[3]));
    float sum = 0.f;
    #pragma unroll
    for (int i = 0; i < 8; ++i) { loc[i] = expf(loc[i] - mx); sum += loc[i]; }
    #pragma unroll
    for (int m = 32; m >= 1; m >>= 1) sum += __shfl_xor(sum, m);
    if ((tid & 63) == 0) red2[w] = sum;
    __syncthreads();
    sum = red2[0] + red2[1] + red2[2] + red2[3];
    float inv = 1.f / sum;
    #pragma unroll
    for (int i = 0; i < 8; ++i)
        wts[(size_t)b * NS + tid + i * 256] = loc[i] * inv;
}

// ---------- Kernel C2a: partial weighted sums (reads Ebf bf16) --------------
__global__ void attnout1_kernel(const unsigned short* __restrict__ Ebf,
                                const float* __restrict__ wts,
                                const int* __restrict__ lens,
                                float* __restrict__ part)
{
    int b  = blockIdx.x;                  // 32
    int ch = blockIdx.y;                  // 16 s-chunks of 128
    int s0 = ch * 128;
    int t  = threadIdx.x;                 // 256
    int len = lens[b];
    float* po = part + ((size_t)ch * NB + b) * NH;
    if (len > 0 && s0 >= len) {
        *(float4*)(po + t * 4) = (float4){0.f, 0.f, 0.f, 0.f};
        return;
    }
    __shared__ float wsh[128];
    if (t < 128) wsh[t] = wts[(size_t)b * NS + s0 + t];
    __syncthreads();
    int h0 = t * 4;
    const unsigned short* Eb = Ebf + ((size_t)b * NS + s0) * NH + h0;
    float4 acc = {0.f, 0.f, 0.f, 0.f};
    for (int s = 0; s < 128; ++s) {
        float w = wsh[s];
        ushort4v e = *(const ushort4v*)(Eb + (size_t)s * NH);
        acc.x += w * bf2f(e[0]); acc.y += w * bf2f(e[1]);
        acc.z += w * bf2f(e[2]); acc.w += w * bf2f(e[3]);
    }
    *(float4*)(po + h0) = acc;
}

// ---------- Kernel C2b: reduce 16 partials -> out ---------------------------
__global__ void attnout2_kernel(const float* __restrict__ part,
                                float* __restrict__ out)
{
    int b = blockIdx.x, t = threadIdx.x;  // 32 x 256
    float4 acc = {0.f, 0.f, 0.f, 0.f};
    #pragma unroll
    for (int c = 0; c < 16; ++c) {
        float4 p = *(const float4*)(part + ((size_t)c * NB + b) * NH + t * 4);
        acc.x += p.x; acc.y += p.y; acc.z += p.z; acc.w += p.w;
    }
    *(float4*)(out + (size_t)b * NH + t * 4) = acc;
}

// ---------- launch ----------------------------------------------------------
extern "C" void kernel_launch(void* const* d_in, const int* in_sizes, int n_in,
                              void* d_out, int out_size, void* d_ws, size_t ws_size,
                              hipStream_t stream)
{
    const float* q    = (const float*)d_in[0];
    const float* E    = (const float*)d_in[1];
    const int*   lens = (const int*)d_in[2];
    const float* Wh   = (const float*)d_in[3];
    const float* Ws   = (const float*)d_in[4];
    const float* v    = (const float*)d_in[5];
    float* out = (float*)d_out;

    float* ws     = (float*)d_ws;
    float* projs  = ws;                          // 32768 f
    float* spart  = projs + 32 * 1024;           // 4*65536 f
    float* wts    = spart + 4 * NB * NS;         // 65536 f
    float* part   = wts + NB * NS;               // 16*32*1024 f
    unsigned short* WhP = (unsigned short*)(part + 16 * NB * NH);   // 2 MB
    unsigned short* Ebf = WhP + 1024 * 1024;                        // 128 MB

    conve_kernel      <<<NB * NS, 256, 0, stream>>>(E, lens, Ebf);
    convw_projs_kernel<<<256, 256, 0, stream>>>(Wh, WhP, q, Ws, projs);
    scores_kernel     <<<2048, 256, 0, stream>>>(Ebf, WhP, projs, v, lens, spart);
    softmax_kernel    <<<NB, 256, 0, stream>>>(spart, lens, wts);
    attnout1_kernel   <<<dim3(NB, 16), 256, 0, stream>>>(Ebf, wts, lens, part);
    attnout2_kernel   <<<NB, 256, 0, stream>>>(part, out);
}

// Round 14
// 166.762 us; speedup vs baseline: 1.1095x; 1.1095x over previous
//
#include <hip/hip_runtime.h>
#include <hip/hip_bf16.h>
#include <stdint.h>

#define NB 32
#define NS 2048
#define NH 1024

typedef __attribute__((ext_vector_type(8))) unsigned short ushort8v;
typedef __attribute__((ext_vector_type(4))) unsigned short ushort4v;
typedef __attribute__((ext_vector_type(8))) __bf16 bf16x8;
typedef __attribute__((ext_vector_type(4))) float floatx4;

__device__ __forceinline__ unsigned short f2bf(float f) {
    union { float f; unsigned int u; } x; x.f = f;
    unsigned int r = x.u + 0x7fffu + ((x.u >> 16) & 1u);
    return (unsigned short)(r >> 16);
}
__device__ __forceinline__ float bf2f(unsigned short u) {
    union { unsigned int u; float f; } x; x.u = ((unsigned int)u) << 16;
    return x.f;
}
__device__ __forceinline__ float tanh_fast(float x) {
    float e2 = __expf(2.0f * x);
    return 1.0f - 2.0f * __builtin_amdgcn_rcpf(e2 + 1.0f);
}
__device__ __forceinline__ void gload_lds16(const void* g, void* l) {
    __builtin_amdgcn_global_load_lds(
        (const __attribute__((address_space(1))) unsigned int*)g,
        (__attribute__((address_space(3))) unsigned int*)l, 16, 0, 0);
}

// ---------- Kernel E: E f32 -> Ebf bf16 (valid rows; ALL rows if len==0) ----
__global__ void conve_kernel(const float* __restrict__ E,
                             const int* __restrict__ lens,
                             unsigned short* __restrict__ Ebf)
{
    int r = blockIdx.x;                   // 65536 rows
    int len = lens[r >> 11];
    if (len != 0 && (r & (NS - 1)) >= len) return;
    int t = threadIdx.x;                  // 256
    float4 f = *(const float4*)(E + (size_t)r * NH + t * 4);
    ushort4v u;
    u[0] = f2bf(f.x); u[1] = f2bf(f.y); u[2] = f2bf(f.z); u[3] = f2bf(f.w);
    *(ushort4v*)(Ebf + (size_t)r * NH + t * 4) = u;
}

// ---------- Kernel WP: fused convw (blocks 0..127) + projs (blocks 128..255) -
__global__ void convw_projs_kernel(const float* __restrict__ Wh,
                                   unsigned short* __restrict__ WhP,
                                   const float* __restrict__ q,
                                   const float* __restrict__ Ws,
                                   float* __restrict__ projs)
{
    int t = threadIdx.x;                  // 256
    if (blockIdx.x < 128) {
        int kb = blockIdx.x;
        int n  = t * 4;
        int ni = n & 15, nh = n >> 4;
        for (int i = 0; i < 8; ++i) {
            int k = kb * 8 + i;
            float4 w = *(const float4*)(Wh + (size_t)k * NH + n);
            size_t base = (size_t)nh * 16384 + (size_t)(k >> 5) * 512 + (k & 31);
            WhP[base + (size_t)(ni + 0) * 32] = f2bf(w.x);
            WhP[base + (size_t)(ni + 1) * 32] = f2bf(w.y);
            WhP[base + (size_t)(ni + 2) * 32] = f2bf(w.z);
            WhP[base + (size_t)(ni + 3) * 32] = f2bf(w.w);
        }
        return;
    }
    int lb = blockIdx.x - 128;            // 32 b x 4 d-chunks
    int b  = lb >> 2;
    int d0 = (lb & 3) * 256;
    int kg = t >> 6;
    int dc = t & 63;
    const float* qb = q + (size_t)b * NH;
    float4 acc = {0.f, 0.f, 0.f, 0.f};
    for (int k = kg * 256; k < kg * 256 + 256; ++k) {
        float qv = qb[k];
        float4 wv = *(const float4*)(Ws + (size_t)k * NH + d0 + dc * 4);
        acc.x += qv * wv.x; acc.y += qv * wv.y;
        acc.z += qv * wv.z; acc.w += qv * wv.w;
    }
    __shared__ float4 red[4][64];
    red[kg][dc] = acc;
    __syncthreads();
    if (t < 64) {
        float4 s = red[0][t];
        float4 s1 = red[1][t], s2 = red[2][t], s3 = red[3][t];
        s.x += s1.x + s2.x + s3.x; s.y += s1.y + s2.y + s3.y;
        s.z += s1.z + s2.z + s3.z; s.w += s1.w + s2.w + s3.w;
        *(float4*)(projs + (size_t)b * NH + d0 + t * 4) = s;
    }
}

// ---------- Kernel B: 128x256 GEMM, BK=32, 8 waves, 3-buffer ring -----------
// BALANCED XCD swizzle: x=wgid&7 (XCD), i=wgid>>3, cb=i&3, rt=(i>>2)*8+x.
// Row-tiles round-robin across XCDs (equal expected work per XCD since each
// XCD gets 2 tiles of every batch); a row-tile's 4 cb-blocks stay on one XCD,
// dispatch-adjacent (L2 reuse of the A-tile preserved).
__global__ __launch_bounds__(512) void scores_kernel(
    const unsigned short* __restrict__ Ebf, const unsigned short* __restrict__ WhP,
    const float* __restrict__ projs, const float* __restrict__ v,
    const int* __restrict__ lens, float* __restrict__ spart)
{
    __shared__ __align__(16) unsigned short Al[3][4096];  // [128 rows][32 sh] x3
    __shared__ __align__(16) unsigned short Bl[3][8192];  // 16 x 1KB units  x3
    __shared__ float sc[4][128];

    const int tid  = threadIdx.x;
    const int wgid = blockIdx.x;
    const int x    = wgid & 7;            // XCD
    const int i    = wgid >> 3;
    const int cb   = i & 3;               // 0..3: cols [cb*256, +256)
    const int rt   = (i >> 2) * 8 + x;    // row tile 0..511, round-robin/XCD
    const int brow = rt * 128;
    const int b    = brow >> 11;
    const int sloc = brow & (NS - 1);
    if (sloc >= lens[b]) return;

    const int wave = tid >> 6;            // 0..7
    const int lane = tid & 63;
    const int l15 = lane & 15;
    const int l16 = lane >> 4;
    const int wr = wave >> 2;             // 0..1 row grp (64 rows)
    const int wc = wave & 3;              // 0..3 col grp (64 cols)

    floatx4 acc[4][4];
    #pragma unroll
    for (int m = 0; m < 4; ++m)
        #pragma unroll
        for (int c = 0; c < 4; ++c) acc[m][c] = (floatx4){0.f, 0.f, 0.f, 0.f};

    // source-side swizzle (involution, same for A and B)
    const int ssw = ((lane & 3) ^ ((lane >> 3) & 3)) * 8;

    const unsigned short* Asrc = Ebf
        + (size_t)(brow + wave * 16 + (lane >> 2)) * NH + ssw;
    const unsigned short* Bsrc0 = WhP
        + (size_t)(cb * 16 + wave * 2) * 16384 + (lane >> 2) * 32 + ssw;
    const unsigned short* Bsrc1 = Bsrc0 + 16384;

    #define STAGE(buf, kc)                                                     \
    {                                                                          \
        gload_lds16(Asrc + (size_t)(kc) * 32, (void*)&Al[buf][wave * 512]);    \
        gload_lds16(Bsrc0 + (size_t)(kc) * 512, (void*)&Bl[buf][(wave * 2) * 512]); \
        gload_lds16(Bsrc1 + (size_t)(kc) * 512, (void*)&Bl[buf][(wave * 2 + 1) * 512]); \
    }

    const int aslot = (l16 ^ ((l15 >> 1) & 3)) * 8;
    const int bslot = aslot;

    #define COMPUTE(buf)                                                       \
    {                                                                          \
        bf16x8 a[4], bfr[4];                                                   \
        _Pragma("unroll")                                                      \
        for (int m = 0; m < 4; ++m)                                            \
            a[m] = __builtin_bit_cast(bf16x8, *(const ushort8v*)               \
                &Al[buf][(wr * 64 + m * 16 + l15) * 32 + aslot]);              \
        _Pragma("unroll")                                                      \
        for (int c = 0; c < 4; ++c)                                            \
            bfr[c] = __builtin_bit_cast(bf16x8, *(const ushort8v*)             \
                &Bl[buf][(wc * 4 + c) * 512 + l15 * 32 + bslot]);              \
        __builtin_amdgcn_s_setprio(1);                                         \
        _Pragma("unroll")                                                      \
        for (int m = 0; m < 4; ++m)                                            \
            _Pragma("unroll")                                                  \
            for (int c = 0; c < 4; ++c)                                        \
                acc[m][c] = __builtin_amdgcn_mfma_f32_16x16x32_bf16(           \
                    a[m], bfr[c], acc[m][c], 0, 0, 0);                         \
        __builtin_amdgcn_s_setprio(0);                                         \
    }

    STAGE(0, 0);

    for (int kc = 0; kc < 31; ++kc) {
        const int rbuf = kc % 3;
        const int sbuf = (kc + 1) % 3;
        STAGE(sbuf, kc + 1);
        asm volatile("s_waitcnt vmcnt(3)" ::: "memory");  // my kc-loads landed
        __builtin_amdgcn_sched_barrier(0);
        __builtin_amdgcn_s_barrier();                     // everyone's landed
        COMPUTE(rbuf);
    }
    // tail: kc = 31 (staged in iter 30; nothing else in flight)
    asm volatile("s_waitcnt vmcnt(0)" ::: "memory");
    __builtin_amdgcn_sched_barrier(0);
    __builtin_amdgcn_s_barrier();
    COMPUTE(31 % 3);
    #undef STAGE
    #undef COMPUTE

    // epilogue: partial score over this cb's 256 cols
    float psv[4], vv[4];
    #pragma unroll
    for (int c = 0; c < 4; ++c) {
        int col = cb * 256 + wc * 64 + c * 16 + l15;
        psv[c] = projs[(size_t)b * NH + col];
        vv[c]  = v[col];
    }
    #pragma unroll
    for (int m = 0; m < 4; ++m) {
        float sp[4] = {0.f, 0.f, 0.f, 0.f};
        #pragma unroll
        for (int c = 0; c < 4; ++c)
            #pragma unroll
            for (int i2 = 0; i2 < 4; ++i2)
                sp[i2] += tanh_fast(acc[m][c][i2] + psv[c]) * vv[c];
        #pragma unroll
        for (int i2 = 0; i2 < 4; ++i2) {
            float s = sp[i2];
            s += __shfl_xor(s, 1);
            s += __shfl_xor(s, 2);
            s += __shfl_xor(s, 4);
            s += __shfl_xor(s, 8);
            if (l15 == 0) sc[wc][wr * 64 + m * 16 + l16 * 4 + i2] = s;
        }
    }
    __syncthreads();
    if (tid < 128) {
        float s = sc[0][tid] + sc[1][tid] + sc[2][tid] + sc[3][tid];
        spart[(size_t)cb * (NB * NS) + brow + tid] = s;
    }
}

// ---------- Kernel C1: masked softmax (sums 4 column partials) --------------
__global__ void softmax_kernel(const float* __restrict__ spart,
                               const int* __restrict__ lens,
                               float* __restrict__ wts)
{
    int b = blockIdx.x, tid = threadIdx.x;      // 32 x 256
    int len = lens[b];
    float loc[8];
    float mx = -3e38f;
    #pragma unroll
    for (int i = 0; i < 8; ++i) {
        int s = tid + i * 256;
        float val = -1e9f;
        if (s < len) {
            val = 0.f;
            #pragma unroll
            for (int c = 0; c < 4; ++c)
                val += spart[(size_t)c * (NB * NS) + (size_t)b * NS + s];
        }
        loc[i] = val;
        mx = fmaxf(mx, val);
    }
    #pragma unroll
    for (int m = 32; m >= 1; m >>= 1) mx = fmaxf(mx, __shfl_xor(mx, m));
    __shared__ float red[4], red2[4];
    int w = tid >> 6;
    if ((tid & 63) == 0) red[w] = mx;
    __syncthreads();
    mx = fmaxf(fmaxf(red[0], red[1]), fmaxf(red[2], red[3]));
    float sum = 0.f;
    #pragma unroll
    for (int i = 0; i < 8; ++i) { loc[i] = expf(loc[i] - mx); sum += loc[i]; }
    #pragma unroll
    for (int m = 32; m >= 1; m >>= 1) sum += __shfl_xor(sum, m);
    if ((tid & 63) == 0) red2[w] = sum;
    __syncthreads();
    sum = red2[0] + red2[1] + red2[2] + red2[3];
    float inv = 1.f / sum;
    #pragma unroll
    for (int i = 0; i < 8; ++i)
        wts[(size_t)b * NS + tid + i * 256] = loc[i] * inv;
}

// ---------- Kernel C2a: partial weighted sums (reads Ebf bf16) --------------
__global__ void attnout1_kernel(const unsigned short* __restrict__ Ebf,
                                const float* __restrict__ wts,
                                const int* __restrict__ lens,
                                float* __restrict__ part)
{
    int b  = blockIdx.x;                  // 32
    int ch = blockIdx.y;                  // 16 s-chunks of 128
    int s0 = ch * 128;
    int t  = threadIdx.x;                 // 256
    int len = lens[b];
    float* po = part + ((size_t)ch * NB + b) * NH;
    if (len > 0 && s0 >= len) {
        *(float4*)(po + t * 4) = (float4){0.f, 0.f, 0.f, 0.f};
        return;
    }
    __shared__ float wsh[128];
    if (t < 128) wsh[t] = wts[(size_t)b * NS + s0 + t];
    __syncthreads();
    int h0 = t * 4;
    const unsigned short* Eb = Ebf + ((size_t)b * NS + s0) * NH + h0;
    float4 acc = {0.f, 0.f, 0.f, 0.f};
    for (int s = 0; s < 128; ++s) {
        float w = wsh[s];
        ushort4v e = *(const ushort4v*)(Eb + (size_t)s * NH);
        acc.x += w * bf2f(e[0]); acc.y += w * bf2f(e[1]);
        acc.z += w * bf2f(e[2]); acc.w += w * bf2f(e[3]);
    }
    *(float4*)(po + h0) = acc;
}

// ---------- Kernel C2b: reduce 16 partials -> out ---------------------------
__global__ void attnout2_kernel(const float* __restrict__ part,
                                float* __restrict__ out)
{
    int b = blockIdx.x, t = threadIdx.x;  // 32 x 256
    float4 acc = {0.f, 0.f, 0.f, 0.f};
    #pragma unroll
    for (int c = 0; c < 16; ++c) {
        float4 p = *(const float4*)(part + ((size_t)c * NB + b) * NH + t * 4);
        acc.x += p.x; acc.y += p.y; acc.z += p.z; acc.w += p.w;
    }
    *(float4*)(out + (size_t)b * NH + t * 4) = acc;
}

// ---------- launch ----------------------------------------------------------
extern "C" void kernel_launch(void* const* d_in, const int* in_sizes, int n_in,
                              void* d_out, int out_size, void* d_ws, size_t ws_size,
                              hipStream_t stream)
{
    const float* q    = (const float*)d_in[0];
    const float* E    = (const float*)d_in[1];
    const int*   lens = (const int*)d_in[2];
    const float* Wh   = (const float*)d_in[3];
    const float* Ws   = (const float*)d_in[4];
    const float* v    = (const float*)d_in[5];
    float* out = (float*)d_out;

    float* ws     = (float*)d_ws;
    float* projs  = ws;                          // 32768 f
    float* spart  = projs + 32 * 1024;           // 4*65536 f
    float* wts    = spart + 4 * NB * NS;         // 65536 f
    float* part   = wts + NB * NS;               // 16*32*1024 f
    unsigned short* WhP = (unsigned short*)(part + 16 * NB * NH);   // 2 MB
    unsigned short* Ebf = WhP + 1024 * 1024;                        // 128 MB

    conve_kernel      <<<NB * NS, 256, 0, stream>>>(E, lens, Ebf);
    convw_projs_kernel<<<256, 256, 0, stream>>>(Wh, WhP, q, Ws, projs);
    scores_kernel     <<<2048, 512, 0, stream>>>(Ebf, WhP, projs, v, lens, spart);
    softmax_kernel    <<<NB, 256, 0, stream>>>(spart, lens, wts);
    attnout1_kernel   <<<dim3(NB, 16), 256, 0, stream>>>(Ebf, wts, lens, part);
    attnout2_kernel   <<<NB, 256, 0, stream>>>(part, out);
}

// Round 15
// 148.564 us; speedup vs baseline: 1.2454x; 1.1225x over previous
//
#include <hip/hip_runtime.h>
#include <hip/hip_bf16.h>
#include <stdint.h>

#define NB 32
#define NS 2048
#define NH 1024

typedef __attribute__((ext_vector_type(8))) unsigned short ushort8v;
typedef __attribute__((ext_vector_type(4))) unsigned short ushort4v;
typedef __attribute__((ext_vector_type(8))) __bf16 bf16x8;
typedef __attribute__((ext_vector_type(4))) float floatx4;

__device__ __forceinline__ unsigned short f2bf(float f) {
    union { float f; unsigned int u; } x; x.f = f;
    unsigned int r = x.u + 0x7fffu + ((x.u >> 16) & 1u);
    return (unsigned short)(r >> 16);
}
__device__ __forceinline__ float bf2f(unsigned short u) {
    union { unsigned int u; float f; } x; x.u = ((unsigned int)u) << 16;
    return x.f;
}
__device__ __forceinline__ float tanh_fast(float x) {
    float e2 = __expf(2.0f * x);
    return 1.0f - 2.0f * __builtin_amdgcn_rcpf(e2 + 1.0f);
}
__device__ __forceinline__ void gload_lds16(const void* g, void* l) {
    __builtin_amdgcn_global_load_lds(
        (const __attribute__((address_space(1))) unsigned int*)g,
        (__attribute__((address_space(3))) unsigned int*)l, 16, 0, 0);
}

// ---------- Kernel P: fused prep --------------------------------------------
// blocks 0..127: pack Wh -> WhP; blocks 128..255: projs = q@Ws;
// blocks 256..65791: E f32 -> Ebf bf16 (valid rows; ALL rows if len==0).
// Small blocks overlap with the HBM-bound conve part instead of serializing.
__global__ void prep_kernel(const float* __restrict__ E,
                            const int* __restrict__ lens,
                            unsigned short* __restrict__ Ebf,
                            const float* __restrict__ Wh,
                            unsigned short* __restrict__ WhP,
                            const float* __restrict__ q,
                            const float* __restrict__ Ws,
                            float* __restrict__ projs)
{
    const int bid = blockIdx.x;
    const int t   = threadIdx.x;          // 256
    if (bid >= 256) {                     // ---- conve part ----
        int r = bid - 256;                // 65536 rows
        int len = lens[r >> 11];
        if (len != 0 && (r & (NS - 1)) >= len) return;
        float4 f = *(const float4*)(E + (size_t)r * NH + t * 4);
        ushort4v u;
        u[0] = f2bf(f.x); u[1] = f2bf(f.y); u[2] = f2bf(f.z); u[3] = f2bf(f.w);
        *(ushort4v*)(Ebf + (size_t)r * NH + t * 4) = u;
        return;
    }
    if (bid < 128) {                      // ---- convw part ----
        int kb = bid;
        int n  = t * 4;
        int ni = n & 15, nh = n >> 4;
        for (int i = 0; i < 8; ++i) {
            int k = kb * 8 + i;
            float4 w = *(const float4*)(Wh + (size_t)k * NH + n);
            size_t base = (size_t)nh * 16384 + (size_t)(k >> 5) * 512 + (k & 31);
            WhP[base + (size_t)(ni + 0) * 32] = f2bf(w.x);
            WhP[base + (size_t)(ni + 1) * 32] = f2bf(w.y);
            WhP[base + (size_t)(ni + 2) * 32] = f2bf(w.z);
            WhP[base + (size_t)(ni + 3) * 32] = f2bf(w.w);
        }
        return;
    }
    {                                     // ---- projs part ----
        int lb = bid - 128;               // 32 b x 4 d-chunks
        int b  = lb >> 2;
        int d0 = (lb & 3) * 256;
        int kg = t >> 6;
        int dc = t & 63;
        const float* qb = q + (size_t)b * NH;
        float4 acc = {0.f, 0.f, 0.f, 0.f};
        for (int k = kg * 256; k < kg * 256 + 256; ++k) {
            float qv = qb[k];
            float4 wv = *(const float4*)(Ws + (size_t)k * NH + d0 + dc * 4);
            acc.x += qv * wv.x; acc.y += qv * wv.y;
            acc.z += qv * wv.z; acc.w += qv * wv.w;
        }
        __shared__ float4 red[4][64];
        red[kg][dc] = acc;
        __syncthreads();
        if (t < 64) {
            float4 s = red[0][t];
            float4 s1 = red[1][t], s2 = red[2][t], s3 = red[3][t];
            s.x += s1.x + s2.x + s3.x; s.y += s1.y + s2.y + s3.y;
            s.z += s1.z + s2.z + s3.z; s.w += s1.w + s2.w + s3.w;
            *(float4*)(projs + (size_t)b * NH + d0 + t * 4) = s;
        }
    }
}

// ---------- Kernel B: 128x256 GEMM, BK=32, 8 waves, 3-buffer ring -----------
// (byte-exact round-11 structure: XCD-chunked swizzle, single barrier/K-step,
// counted vmcnt(3), both-side LDS swizzles, tanh.v epilogue)
__global__ __launch_bounds__(512) void scores_kernel(
    const unsigned short* __restrict__ Ebf, const unsigned short* __restrict__ WhP,
    const float* __restrict__ projs, const float* __restrict__ v,
    const int* __restrict__ lens, float* __restrict__ spart)
{
    __shared__ __align__(16) unsigned short Al[3][4096];  // [128 rows][32 sh] x3
    __shared__ __align__(16) unsigned short Bl[3][8192];  // 16 x 1KB units  x3
    __shared__ float sc[4][128];

    const int tid  = threadIdx.x;
    const int wgid = blockIdx.x;
    const int vid  = (wgid & 7) * 256 + (wgid >> 3);   // XCD-chunked swizzle
    const int brow = (vid >> 2) * 128;
    const int cb   = vid & 3;             // 0..3: cols [cb*256, +256)
    const int b    = brow >> 11;
    const int sloc = brow & (NS - 1);
    if (sloc >= lens[b]) return;

    const int wave = tid >> 6;            // 0..7
    const int lane = tid & 63;
    const int l15 = lane & 15;
    const int l16 = lane >> 4;
    const int wr = wave >> 2;             // 0..1 row grp (64 rows)
    const int wc = wave & 3;              // 0..3 col grp (64 cols)

    floatx4 acc[4][4];
    #pragma unroll
    for (int m = 0; m < 4; ++m)
        #pragma unroll
        for (int c = 0; c < 4; ++c) acc[m][c] = (floatx4){0.f, 0.f, 0.f, 0.f};

    const int ssw = ((lane & 3) ^ ((lane >> 3) & 3)) * 8;

    const unsigned short* Asrc = Ebf
        + (size_t)(brow + wave * 16 + (lane >> 2)) * NH + ssw;
    const unsigned short* Bsrc0 = WhP
        + (size_t)(cb * 16 + wave * 2) * 16384 + (lane >> 2) * 32 + ssw;
    const unsigned short* Bsrc1 = Bsrc0 + 16384;

    #define STAGE(buf, kc)                                                     \
    {                                                                          \
        gload_lds16(Asrc + (size_t)(kc) * 32, (void*)&Al[buf][wave * 512]);    \
        gload_lds16(Bsrc0 + (size_t)(kc) * 512, (void*)&Bl[buf][(wave * 2) * 512]); \
        gload_lds16(Bsrc1 + (size_t)(kc) * 512, (void*)&Bl[buf][(wave * 2 + 1) * 512]); \
    }

    const int aslot = (l16 ^ ((l15 >> 1) & 3)) * 8;
    const int bslot = aslot;

    #define COMPUTE(buf)                                                       \
    {                                                                          \
        bf16x8 a[4], bfr[4];                                                   \
        _Pragma("unroll")                                                      \
        for (int m = 0; m < 4; ++m)                                            \
            a[m] = __builtin_bit_cast(bf16x8, *(const ushort8v*)               \
                &Al[buf][(wr * 64 + m * 16 + l15) * 32 + aslot]);              \
        _Pragma("unroll")                                                      \
        for (int c = 0; c < 4; ++c)                                            \
            bfr[c] = __builtin_bit_cast(bf16x8, *(const ushort8v*)             \
                &Bl[buf][(wc * 4 + c) * 512 + l15 * 32 + bslot]);              \
        __builtin_amdgcn_s_setprio(1);                                         \
        _Pragma("unroll")                                                      \
        for (int m = 0; m < 4; ++m)                                            \
            _Pragma("unroll")                                                  \
            for (int c = 0; c < 4; ++c)                                        \
                acc[m][c] = __builtin_amdgcn_mfma_f32_16x16x32_bf16(           \
                    a[m], bfr[c], acc[m][c], 0, 0, 0);                         \
        __builtin_amdgcn_s_setprio(0);                                         \
    }

    STAGE(0, 0);

    for (int kc = 0; kc < 31; ++kc) {
        const int rbuf = kc % 3;
        const int sbuf = (kc + 1) % 3;
        STAGE(sbuf, kc + 1);
        asm volatile("s_waitcnt vmcnt(3)" ::: "memory");
        __builtin_amdgcn_sched_barrier(0);
        __builtin_amdgcn_s_barrier();
        COMPUTE(rbuf);
    }
    asm volatile("s_waitcnt vmcnt(0)" ::: "memory");
    __builtin_amdgcn_sched_barrier(0);
    __builtin_amdgcn_s_barrier();
    COMPUTE(31 % 3);
    #undef STAGE
    #undef COMPUTE

    float psv[4], vv[4];
    #pragma unroll
    for (int c = 0; c < 4; ++c) {
        int col = cb * 256 + wc * 64 + c * 16 + l15;
        psv[c] = projs[(size_t)b * NH + col];
        vv[c]  = v[col];
    }
    #pragma unroll
    for (int m = 0; m < 4; ++m) {
        float sp[4] = {0.f, 0.f, 0.f, 0.f};
        #pragma unroll
        for (int c = 0; c < 4; ++c)
            #pragma unroll
            for (int i2 = 0; i2 < 4; ++i2)
                sp[i2] += tanh_fast(acc[m][c][i2] + psv[c]) * vv[c];
        #pragma unroll
        for (int i2 = 0; i2 < 4; ++i2) {
            float s = sp[i2];
            s += __shfl_xor(s, 1);
            s += __shfl_xor(s, 2);
            s += __shfl_xor(s, 4);
            s += __shfl_xor(s, 8);
            if (l15 == 0) sc[wc][wr * 64 + m * 16 + l16 * 4 + i2] = s;
        }
    }
    __syncthreads();
    if (tid < 128) {
        float s = sc[0][tid] + sc[1][tid] + sc[2][tid] + sc[3][tid];
        spart[(size_t)cb * (NB * NS) + brow + tid] = s;
    }
}

// ---------- Kernel C: attnout with inline softmax ---------------------------
// Each (b, chunk) block recomputes the batch softmax stats from spart (L2-hot,
// 32 KB + 8 exp/thread) and forms its own 128 weights locally; then the
// bf16 weighted sum over its chunk. Eliminates the softmax kernel + wts buf.
__global__ void attnout1_kernel(const unsigned short* __restrict__ Ebf,
                                const float* __restrict__ spart,
                                const int* __restrict__ lens,
                                float* __restrict__ part)
{
    int b  = blockIdx.x;                  // 32
    int ch = blockIdx.y;                  // 16 s-chunks of 128
    int s0 = ch * 128;
    int t  = threadIdx.x;                 // 256
    int len = lens[b];
    float* po = part + ((size_t)ch * NB + b) * NH;
    if (len > 0 && s0 >= len) {           // fully masked chunk
        *(float4*)(po + t * 4) = (float4){0.f, 0.f, 0.f, 0.f};
        return;
    }
    const float* p0 = spart + (size_t)b * NS;
    // --- inline masked softmax stats over the full row ---
    float loc[8];
    float mx = -3e38f;
    #pragma unroll
    for (int i = 0; i < 8; ++i) {
        int s = t + i * 256;
        float val = -1e9f;
        if (s < len) {
            val = 0.f;
            #pragma unroll
            for (int c = 0; c < 4; ++c) val += p0[(size_t)c * (NB * NS) + s];
        }
        loc[i] = val;
        mx = fmaxf(mx, val);
    }
    #pragma unroll
    for (int m = 32; m >= 1; m >>= 1) mx = fmaxf(mx, __shfl_xor(mx, m));
    __shared__ float red[4], red2[4];
    __shared__ float wsh[128];
    int w = t >> 6;
    if ((t & 63) == 0) red[w] = mx;
    __syncthreads();
    mx = fmaxf(fmaxf(red[0], red[1]), fmaxf(red[2], red[3]));
    float sum = 0.f;
    #pragma unroll
    for (int i = 0; i < 8; ++i) sum += expf(loc[i] - mx);
    #pragma unroll
    for (int m = 32; m >= 1; m >>= 1) sum += __shfl_xor(sum, m);
    if ((t & 63) == 0) red2[w] = sum;
    __syncthreads();
    sum = red2[0] + red2[1] + red2[2] + red2[3];
    float inv = 1.f / sum;
    // weights for this chunk only
    if (t < 128) {
        int s = s0 + t;
        float val = -1e9f;
        if (s < len) {
            val = 0.f;
            #pragma unroll
            for (int c = 0; c < 4; ++c) val += p0[(size_t)c * (NB * NS) + s];
        }
        wsh[t] = expf(val - mx) * inv;
    }
    __syncthreads();
    // --- weighted sum over the chunk (bf16 E) ---
    int h0 = t * 4;
    const unsigned short* Eb = Ebf + ((size_t)b * NS + s0) * NH + h0;
    float4 acc = {0.f, 0.f, 0.f, 0.f};
    for (int s = 0; s < 128; ++s) {
        float wv = wsh[s];
        ushort4v e = *(const ushort4v*)(Eb + (size_t)s * NH);
        acc.x += wv * bf2f(e[0]); acc.y += wv * bf2f(e[1]);
        acc.z += wv * bf2f(e[2]); acc.w += wv * bf2f(e[3]);
    }
    *(float4*)(po + h0) = acc;
}

// ---------- Kernel D: reduce 16 partials -> out -----------------------------
__global__ void attnout2_kernel(const float* __restrict__ part,
                                float* __restrict__ out)
{
    int b = blockIdx.x, t = threadIdx.x;  // 32 x 256
    float4 acc = {0.f, 0.f, 0.f, 0.f};
    #pragma unroll
    for (int c = 0; c < 16; ++c) {
        float4 p = *(const float4*)(part + ((size_t)c * NB + b) * NH + t * 4);
        acc.x += p.x; acc.y += p.y; acc.z += p.z; acc.w += p.w;
    }
    *(float4*)(out + (size_t)b * NH + t * 4) = acc;
}

// ---------- launch ----------------------------------------------------------
extern "C" void kernel_launch(void* const* d_in, const int* in_sizes, int n_in,
                              void* d_out, int out_size, void* d_ws, size_t ws_size,
                              hipStream_t stream)
{
    const float* q    = (const float*)d_in[0];
    const float* E    = (const float*)d_in[1];
    const int*   lens = (const int*)d_in[2];
    const float* Wh   = (const float*)d_in[3];
    const float* Ws   = (const float*)d_in[4];
    const float* v    = (const float*)d_in[5];
    float* out = (float*)d_out;

    float* ws     = (float*)d_ws;
    float* projs  = ws;                          // 32768 f
    float* spart  = projs + 32 * 1024;           // 4*65536 f
    float* part   = spart + 4 * NB * NS;         // 16*32*1024 f
    unsigned short* WhP = (unsigned short*)(part + 16 * NB * NH);   // 2 MB
    unsigned short* Ebf = WhP + 1024 * 1024;                        // 128 MB

    prep_kernel    <<<256 + NB * NS, 256, 0, stream>>>(E, lens, Ebf, Wh, WhP, q, Ws, projs);
    scores_kernel  <<<2048, 512, 0, stream>>>(Ebf, WhP, projs, v, lens, spart);
    attnout1_kernel<<<dim3(NB, 16), 256, 0, stream>>>(Ebf, spart, lens, part);
    attnout2_kernel<<<NB, 256, 0, stream>>>(part, out);
}